// Round 3
// baseline (833.909 us; speedup 1.0000x reference)
//
#include <hip/hip_runtime.h>

#define THREADS 256
#define EPT 8  // output elems per thread; piece lengths are 16*s^2 (mult of 16) so 8-groups never straddle batches

// Setup: prefix offsets of the packed output, off[b] = sum_{j<b} 16*s_j^2.
__global__ void setup_offsets_kernel(const int* __restrict__ seq,
                                     unsigned int* __restrict__ off) {
    if (threadIdx.x == 0 && blockIdx.x == 0) {
        unsigned int a = 0;
        off[0] = 0u;
        for (int b = 0; b < 8; ++b) {
            unsigned int s = (unsigned int)seq[b];
            a += 16u * s * s;
            off[b + 1] = a;
        }
    }
}

__global__ void __launch_bounds__(THREADS)
unpad_mask_kernel(const float* __restrict__ mask,   // fp16 input promoted to f32 by harness
                  const int* __restrict__ seq,
                  const unsigned int* __restrict__ off,
                  int* __restrict__ out,            // bool output stored as int32
                  unsigned int out_size) {
    __shared__ unsigned int s_off[9];
    __shared__ unsigned int s_len[8];
    if (threadIdx.x < 9) s_off[threadIdx.x] = off[threadIdx.x];
    if (threadIdx.x < 8) s_len[threadIdx.x] = (unsigned int)seq[threadIdx.x];
    __syncthreads();

    unsigned int tid = blockIdx.x * THREADS + threadIdx.x;
    unsigned int g0 = tid * EPT;
    if (g0 >= out_size) return;

    // branchless batch search (offsets are monotone)
    unsigned int b = 0;
#pragma unroll
    for (int j = 1; j < 8; ++j) b += (g0 >= s_off[j]) ? 1u : 0u;

    unsigned int s  = s_len[b];
    unsigned int s2 = s * s;                 // <= 2^22
    unsigned int p  = g0 - s_off[b];         // < 16*s2 <= 2^26

    // r = p mod s2 via 4 conditional subtracts (exact, no division)
    unsigned int r = p;
    if (r >= (s2 << 3)) r -= (s2 << 3);
    if (r >= (s2 << 2)) r -= (s2 << 2);
    if (r >= (s2 << 1)) r -= (s2 << 1);
    if (r >=  s2      ) r -=  s2;

    // row = r / s: r < 2^22 (exact in f32), s <= 2048; IEEE f32 div floor exact here.
    unsigned int row = (unsigned int)((float)r / (float)s);
    int col = (int)r - (int)(row * s);
    if (col < 0)            { row -= 1u; col += (int)s; }
    else if (col >= (int)s) { row += 1u; col -= (int)s; }

    const float* mb = mask + ((size_t)b << 22);  // 2048*2048 elems per batch
    int vals[EPT];
#pragma unroll
    for (int j = 0; j < EPT; ++j) {
        float v = mb[(size_t)row * 2048u + (unsigned int)col];
        vals[j] = (v > 0.5f) ? 1 : 0;
        // advance (col,row) with wrap; head boundary == row wrap at row==s
        col += 1;
        if (col == (int)s) {
            col = 0;
            row += 1u;
            if (row == s) row = 0u;
        }
    }

    int4* o = (int4*)(out + g0);   // g0 is 8-int (32B) aligned
    o[0] = make_int4(vals[0], vals[1], vals[2], vals[3]);
    o[1] = make_int4(vals[4], vals[5], vals[6], vals[7]);
}

extern "C" void kernel_launch(void* const* d_in, const int* in_sizes, int n_in,
                              void* d_out, int out_size, void* d_ws, size_t ws_size,
                              hipStream_t stream) {
    const float* mask = (const float*)d_in[0];
    const int*   seq  = (const int*)d_in[1];
    unsigned int* off = (unsigned int*)d_ws;   // 9 uints of scratch
    int*         out  = (int*)d_out;

    setup_offsets_kernel<<<1, 64, 0, stream>>>(seq, off);

    unsigned int total_threads = ((unsigned int)out_size + EPT - 1u) / EPT;
    unsigned int blocks = (total_threads + THREADS - 1u) / THREADS;
    unpad_mask_kernel<<<blocks, THREADS, 0, stream>>>(mask, seq, off, out,
                                                      (unsigned int)out_size);
}

// Round 4
// 751.483 us; speedup vs baseline: 1.1097x; 1.1097x over previous
//
#include <hip/hip_runtime.h>

#define THREADS 256
#define SRC_PER_THREAD 8   // source elements per thread, stride-64 interleaved within the wave
#define HEADS 16

// ws layout (uint32):
//  [0..8]   off16: output prefix, off16[b] = sum_{j<b} 16*s_j^2
//  [9..17]  soff : source prefix, soff[b]  = sum_{j<b} s_j^2   (soff[8] = total src elems)
//  [18..25] s[b]
//  [26..33] s2[b] = s*s
//  [34..41] inv_s[b] as float bits
__global__ void setup_offsets_kernel(const int* __restrict__ seq,
                                     unsigned int* __restrict__ ws) {
    if (threadIdx.x == 0 && blockIdx.x == 0) {
        unsigned int o16 = 0, os = 0;
        ws[0] = 0u; ws[9] = 0u;
        for (int b = 0; b < 8; ++b) {
            unsigned int s  = (unsigned int)seq[b];
            unsigned int s2 = s * s;
            o16 += 16u * s2;
            os  += s2;
            ws[1 + b]  = o16;
            ws[10 + b] = os;
            ws[18 + b] = s;
            ws[26 + b] = s2;
            ((float*)ws)[34 + b] = 1.0f / (float)s;
        }
    }
}

__global__ void __launch_bounds__(THREADS)
unpad_mask_kernel(const float* __restrict__ mask,     // fp16 promoted to f32 by harness
                  const unsigned int* __restrict__ ws,
                  int* __restrict__ out) {             // bool output as int32
    __shared__ unsigned int off16[9];
    __shared__ unsigned int soff[9];
    __shared__ unsigned int slen[8];
    __shared__ unsigned int ssq[8];
    __shared__ float        sinv[8];

    int tx = threadIdx.x;
    if (tx < 9) { off16[tx] = ws[tx]; soff[tx] = ws[9 + tx]; }
    if (tx < 8) {
        slen[tx] = ws[18 + tx];
        ssq[tx]  = ws[26 + tx];
        sinv[tx] = ((const float*)ws)[34 + tx];
    }
    __syncthreads();

    unsigned int total = soff[8];                       // total source elements
    unsigned int t     = blockIdx.x * THREADS + (unsigned int)tx;
    unsigned int lane  = t & 63u;
    unsigned int wbase = (t >> 6) * (64u * SRC_PER_THREAD);  // wave's 512-elem span
    if (wbase >= total) return;

#pragma unroll
    for (int k = 0; k < SRC_PER_THREAD; ++k) {
        unsigned int g = wbase + (unsigned int)k * 64u + lane;  // coalesced across lanes
        if (g >= total) break;

        // batch search (monotone prefix)
        unsigned int b = 0;
#pragma unroll
        for (int j = 1; j < 8; ++j) b += (g >= soff[j]) ? 1u : 0u;

        unsigned int p = g - soff[b];          // position inside the s*s block, < 2^22
        unsigned int s = slen[b];

        // row = p / s via reciprocal + +/-1 fixup (exact after fixup)
        unsigned int row = (unsigned int)((float)p * sinv[b]);
        int col = (int)p - (int)(row * s);
        if (col < 0)            { row -= 1u; col += (int)s; }
        else if (col >= (int)s) { row += 1u; col -= (int)s; }

        float v = mask[((size_t)b << 22) + (size_t)row * 2048u + (unsigned int)col];
        int o = (v > 0.5f) ? 1 : 0;

        // replicate to 16 heads: out[off16[b] + h*s2 + p]
        unsigned int s2 = ssq[b];
        int* op = out + off16[b] + p;
#pragma unroll
        for (int h = 0; h < HEADS; ++h) {
            *op = o;                            // 256B contiguous per store instr
            op += s2;
        }
    }
}

extern "C" void kernel_launch(void* const* d_in, const int* in_sizes, int n_in,
                              void* d_out, int out_size, void* d_ws, size_t ws_size,
                              hipStream_t stream) {
    const float*  mask = (const float*)d_in[0];
    const int*    seq  = (const int*)d_in[1];
    unsigned int* ws   = (unsigned int*)d_ws;   // 42 uints of scratch
    int*          out  = (int*)d_out;

    setup_offsets_kernel<<<1, 64, 0, stream>>>(seq, ws);

    // worst case: 8 * 2048^2 = 33,554,432 source elems; 2048 per block
    const unsigned int max_src   = 8u * 2048u * 2048u;
    const unsigned int per_block = THREADS * SRC_PER_THREAD;  // 2048
    unsigned int blocks = (max_src + per_block - 1u) / per_block;  // 16384
    unpad_mask_kernel<<<blocks, THREADS, 0, stream>>>(mask, ws, out);
}

// Round 5
// 723.113 us; speedup vs baseline: 1.1532x; 1.0392x over previous
//
#include <hip/hip_runtime.h>

#define THREADS 256
#define WAVES_PB 4      // 256 threads = 4 waves
#define ITERS 4         // source chunks (256 elems) per wave
// worst case chunks: 8 * ceil(2048^2/256) = 131072; per block: 4*4=16 -> 8192 blocks
#define MAX_BLOCKS 8192

// ws layout (uint32):
//  [0..8]   off16 : output prefix, off16[b] = sum_{j<b} 16*s_j^2
//  [9..17]  csum  : chunk prefix,  csum[b]  = sum_{j<b} ceil(s_j^2/256)
//  [18..25] s[b]
//  [26..33] s2[b]
//  [34..41] inv_s[b] (float bits)
__global__ void setup_offsets_kernel(const int* __restrict__ seq,
                                     unsigned int* __restrict__ ws) {
    if (threadIdx.x == 0 && blockIdx.x == 0) {
        unsigned int o16 = 0, cs = 0;
        ws[0] = 0u; ws[9] = 0u;
        for (int b = 0; b < 8; ++b) {
            unsigned int s  = (unsigned int)seq[b];
            unsigned int s2 = s * s;
            o16 += 16u * s2;
            cs  += (s2 + 255u) >> 8;
            ws[1 + b]  = o16;
            ws[10 + b] = cs;
            ws[18 + b] = s;
            ws[26 + b] = s2;
            ((float*)ws)[34 + b] = 1.0f / (float)s;
        }
    }
}

__global__ void __launch_bounds__(THREADS)
unpad_mask_kernel(const float* __restrict__ mask,     // fp16 promoted to f32 by harness
                  const unsigned int* __restrict__ ws,
                  int* __restrict__ out) {             // bool output as int32
    __shared__ unsigned int off16[9];
    __shared__ unsigned int csum[9];
    __shared__ unsigned int slen[8];
    __shared__ unsigned int ssq[8];
    __shared__ float        sinv[8];

    int tx = threadIdx.x;
    if (tx < 9) { off16[tx] = ws[tx]; csum[tx] = ws[9 + tx]; }
    if (tx < 8) {
        slen[tx] = ws[18 + tx];
        ssq[tx]  = ws[26 + tx];
        sinv[tx] = ((const float*)ws)[34 + tx];
    }
    __syncthreads();

    unsigned int nchunks = csum[8];
    unsigned int wave_id = blockIdx.x * WAVES_PB + ((unsigned int)tx >> 6);
    unsigned int lane    = (unsigned int)tx & 63u;

#pragma unroll 1
    for (int it = 0; it < ITERS; ++it) {
        unsigned int chunk = wave_id * ITERS + (unsigned int)it;
        if (chunk >= nchunks) break;

        // batch search over chunk prefix (monotone, wave-uniform)
        unsigned int b = 0;
#pragma unroll
        for (int j = 1; j < 8; ++j) b += (chunk >= csum[j]) ? 1u : 0u;

        unsigned int s    = slen[b];
        unsigned int s2   = ssq[b];
        float        inv  = sinv[b];
        unsigned int p0   = (chunk - csum[b]) << 8;   // batch-local, mult of 256
        unsigned int base = off16[b];
        const float* mb   = mask + ((size_t)b << 22);

        if (s2 - p0 >= 256u) {
            // ---- fast path: full chunk, s >= 17 ----
            unsigned int q   = p0 + (lane << 2);       // this lane's first src elem
            unsigned int row = (unsigned int)((float)q * inv);
            int col = (int)q - (int)(row * s);
            if (col < 0)            { row -= 1u; col += (int)s; }
            else if (col >= (int)s) { row += 1u; col -= (int)s; }

            unsigned int r0 = row;  int c0 = col;
            float v0 = mb[(size_t)r0 * 2048u + (unsigned int)c0];
            c0++; if (c0 == (int)s) { c0 = 0; r0++; }
            float v1 = mb[(size_t)r0 * 2048u + (unsigned int)c0];
            c0++; if (c0 == (int)s) { c0 = 0; r0++; }
            float v2 = mb[(size_t)r0 * 2048u + (unsigned int)c0];
            c0++; if (c0 == (int)s) { c0 = 0; r0++; }
            float v3 = mb[(size_t)r0 * 2048u + (unsigned int)c0];

            int o0 = (v0 > 0.5f) ? 1 : 0;
            int o1 = (v1 > 0.5f) ? 1 : 0;
            int o2 = (v2 > 0.5f) ? 1 : 0;
            int o3 = (v3 > 0.5f) ? 1 : 0;
            int4 o4  = make_int4(o0, o1, o2, o3);
            int2 o2a = make_int2(o0, o1);
            int2 o2b = make_int2(o2, o3);

            if ((s & 1u) == 0u) {
                // even s: every head base is 16B-aligned
                unsigned int off = base + q;
#pragma unroll
                for (int h = 0; h < 16; ++h) {
                    *(int4*)(out + off) = o4;
                    off += s2;
                }
            } else {
                // odd s: alignment class r = h & 3
                unsigned int off = base + q;
#pragma unroll
                for (int h = 0; h < 16; ++h) {
                    if ((h & 3) == 0) {
                        *(int4*)(out + off) = o4;
                    } else if ((h & 3) == 2) {
                        *(int2*)(out + off)     = o2a;
                        *(int2*)(out + off + 2) = o2b;
                    } else {
                        out[off]     = o0;
                        out[off + 1] = o1;
                        out[off + 2] = o2;
                        out[off + 3] = o3;
                    }
                    off += s2;
                }
            }
        } else {
            // ---- fallback: partial tail chunk or tiny s ----
#pragma unroll
            for (int j = 0; j < 4; ++j) {
                unsigned int p = p0 + (lane << 2) + (unsigned int)j;
                if (p >= s2) continue;
                unsigned int row = (unsigned int)((float)p * inv);
                int col = (int)p - (int)(row * s);
                if (col < 0)            { row -= 1u; col += (int)s; }
                else if (col >= (int)s) { row += 1u; col -= (int)s; }
                float v = mb[(size_t)row * 2048u + (unsigned int)col];
                int o = (v > 0.5f) ? 1 : 0;
                unsigned int off = base + p;
#pragma unroll
                for (int h = 0; h < 16; ++h) {
                    out[off] = o;
                    off += s2;
                }
            }
        }
    }
}

extern "C" void kernel_launch(void* const* d_in, const int* in_sizes, int n_in,
                              void* d_out, int out_size, void* d_ws, size_t ws_size,
                              hipStream_t stream) {
    const float*  mask = (const float*)d_in[0];
    const int*    seq  = (const int*)d_in[1];
    unsigned int* ws   = (unsigned int*)d_ws;   // 42 uints of scratch
    int*          out  = (int*)d_out;

    setup_offsets_kernel<<<1, 64, 0, stream>>>(seq, ws);
    unpad_mask_kernel<<<MAX_BLOCKS, THREADS, 0, stream>>>(mask, ws, out);
}